// Round 2
// baseline (282.292 us; speedup 1.0000x reference)
//
#include <hip/hip_runtime.h>
#include <math.h>

#define NE 16
#define HD 1024
#define FD 2048
#define TWO_F 4096

// ws layout in 4-byte elements
#define TOPI_OFF 0        // 256 int
#define TOPW_OFF 256      // 256 float
#define CNT_OFF  512      // 16 int
#define PREF_OFF 528      // 16 int
#define PLIST_OFF 544     // 16*128 int
#define WLIST_OFF 2592    // 16*128 float
#define HBUF_OFF 8192     // 256*2048 float

// decode one fp4 e2m1 nibble and fold in the e8m0 scale (2^(s-127)) via exponent math
__device__ __forceinline__ float fp4_scaled(int nib, int sbits) {
    int c = nib & 7;
    int e = c >> 1;
    int m = c & 1;
    int bits = ((e + sbits - 1) << 23) | ((e > 0) ? (m << 22) : 0);
    bits = (c == 0) ? 0 : bits;
    bits |= (nib & 8) << 28;   // sign
    return __int_as_float(bits);
}

__global__ void routing_kernel(const float* __restrict__ x, const float* __restrict__ rw,
                               int* __restrict__ top_idx, float* __restrict__ top_w) {
    int t = blockIdx.x;
    int tid = threadIdx.x;          // 256
    int e = tid >> 4, seg = tid & 15;
    const float* xr = x + t * HD + seg * 64;
    const float* wr = rw + e * HD + seg * 64;
    float p = 0.f;
    #pragma unroll 8
    for (int i = 0; i < 64; ++i) p += xr[i] * wr[i];
    __shared__ float part[16][16];
    __shared__ float logit[16];
    part[e][seg] = p;
    __syncthreads();
    if (tid < 16) {
        float s = 0.f;
        #pragma unroll
        for (int i = 0; i < 16; ++i) s += part[tid][i];
        logit[tid] = s;
    }
    __syncthreads();
    if (tid == 0) {
        int i0 = 0; float v0 = logit[0];
        #pragma unroll
        for (int i = 1; i < 16; ++i) { if (logit[i] > v0) { v0 = logit[i]; i0 = i; } }
        int i1 = -1; float v1 = -1e30f;
        #pragma unroll
        for (int i = 0; i < 16; ++i) { if (i != i0 && logit[i] > v1) { v1 = logit[i]; i1 = i; } }
        float w0 = 1.f / (1.f + expf(v1 - v0));
        float w1 = 1.f / (1.f + expf(v0 - v1));
        top_idx[t * 2]     = i0;  top_w[t * 2]     = w0;
        top_idx[t * 2 + 1] = i1;  top_w[t * 2 + 1] = w1;
    }
}

__global__ void build_kernel(const int* __restrict__ top_idx, const float* __restrict__ top_w,
                             int* __restrict__ cnt, int* __restrict__ pref,
                             int* __restrict__ plist, float* __restrict__ wlist) {
    int e = threadIdx.x;            // block 64
    __shared__ int scnt[16];
    if (e < 16) {
        int c = 0;
        for (int p = 0; p < 256; ++p) {
            if (top_idx[p] == e) {
                plist[e * 128 + c] = p;       // pair id, t = p>>1
                wlist[e * 128 + c] = top_w[p];
                c++;
            }
        }
        cnt[e] = c;
        scnt[e] = c;
    }
    __syncthreads();
    if (e == 0) {
        int s = 0;
        for (int i = 0; i < 16; ++i) { pref[i] = s; s += scnt[i]; }
    }
}

#define ACC16(acc, Wv) \
    acc = fmaf(Wv[0], xa.x, fmaf(Wv[1], xa.y, fmaf(Wv[2], xa.z, fmaf(Wv[3], xa.w, acc)))); \
    acc = fmaf(Wv[4], xb.x, fmaf(Wv[5], xb.y, fmaf(Wv[6], xb.z, fmaf(Wv[7], xb.w, acc)))); \
    acc = fmaf(Wv[8], xc.x, fmaf(Wv[9], xc.y, fmaf(Wv[10], xc.z, fmaf(Wv[11], xc.w, acc)))); \
    acc = fmaf(Wv[12], xd.x, fmaf(Wv[13], xd.y, fmaf(Wv[14], xd.z, fmaf(Wv[15], xd.w, acc))));

// gu GEMM + SwiGLU. Block: 4 waves, each wave owns f0,f0+1 (2 gate rows + 2 up rows).
__global__ __launch_bounds__(256) void gemm1_kernel(
    const float* __restrict__ x, const int* __restrict__ qblk,
    const int* __restrict__ qscl, const float* __restrict__ bias,
    const int* __restrict__ cnt, const int* __restrict__ pref,
    const int* __restrict__ plist, float* __restrict__ hbuf) {
    int e = blockIdx.x >> 8;
    int fb = blockIdx.x & 255;
    int n = cnt[e];
    if (n == 0) return;
    int wave = threadIdx.x >> 6, lane = threadIdx.x & 63;
    int f0 = (fb * 4 + wave) * 2;

    float wg0[16], wg1[16], wu0[16], wu1[16];
    {
        int rg0 = e * TWO_F + f0;
        int rg1 = rg0 + 1;
        int ru0 = rg0 + FD;
        int ru1 = ru0 + 1;
        int sg0 = qscl[rg0 * 32 + (lane >> 1)];
        int sg1 = qscl[rg1 * 32 + (lane >> 1)];
        int su0 = qscl[ru0 * 32 + (lane >> 1)];
        int su1 = qscl[ru1 * 32 + (lane >> 1)];
        const int* bg0 = qblk + (long)rg0 * 512 + lane * 8;
        const int* bg1 = qblk + (long)rg1 * 512 + lane * 8;
        const int* bu0 = qblk + (long)ru0 * 512 + lane * 8;
        const int* bu1 = qblk + (long)ru1 * 512 + lane * 8;
        #pragma unroll
        for (int i = 0; i < 8; ++i) {
            int b;
            b = bg0[i]; wg0[2*i] = fp4_scaled(b & 15, sg0); wg0[2*i+1] = fp4_scaled((b >> 4) & 15, sg0);
            b = bg1[i]; wg1[2*i] = fp4_scaled(b & 15, sg1); wg1[2*i+1] = fp4_scaled((b >> 4) & 15, sg1);
            b = bu0[i]; wu0[2*i] = fp4_scaled(b & 15, su0); wu0[2*i+1] = fp4_scaled((b >> 4) & 15, su0);
            b = bu1[i]; wu1[2*i] = fp4_scaled(b & 15, su1); wu1[2*i+1] = fp4_scaled((b >> 4) & 15, su1);
        }
    }
    float bg0v = bias[e * TWO_F + f0],      bg1v = bias[e * TWO_F + f0 + 1];
    float bu0v = bias[e * TWO_F + FD + f0], bu1v = bias[e * TWO_F + FD + f0 + 1];
    int base = pref[e];
    const int* pl = plist + e * 128;
    for (int j = 0; j < n; ++j) {
        int t = pl[j] >> 1;
        const float4* xr = (const float4*)(x + (long)t * HD + lane * 16);
        float4 xa = xr[0], xb = xr[1], xc = xr[2], xd = xr[3];
        float ag0 = 0.f, ag1 = 0.f, au0 = 0.f, au1 = 0.f;
        ACC16(ag0, wg0); ACC16(ag1, wg1); ACC16(au0, wu0); ACC16(au1, wu1);
        #pragma unroll
        for (int off = 32; off > 0; off >>= 1) {
            ag0 += __shfl_xor(ag0, off);
            ag1 += __shfl_xor(ag1, off);
            au0 += __shfl_xor(au0, off);
            au1 += __shfl_xor(au1, off);
        }
        if (lane == 0) {
            float g0 = ag0 + bg0v, g1 = ag1 + bg1v;
            float u0 = au0 + bu0v, u1 = au1 + bu1v;
            float h0 = (g0 / (1.f + expf(-g0))) * u0;
            float h1 = (g1 / (1.f + expf(-g1))) * u1;
            float* hp = hbuf + (long)(base + j) * FD + f0;
            hp[0] = h0; hp[1] = h1;
        }
    }
}

// down GEMM + bias + routing-weight combine. Block: 4 waves, each owns h0,h0+1 rows.
__global__ __launch_bounds__(256) void gemm2_kernel(
    const float* __restrict__ hbuf, const int* __restrict__ qblk,
    const int* __restrict__ qscl, const float* __restrict__ bias,
    const int* __restrict__ cnt, const int* __restrict__ pref,
    const int* __restrict__ plist, const float* __restrict__ wlist,
    float* __restrict__ out) {
    int e = blockIdx.x >> 7;
    int hb = blockIdx.x & 127;
    int n = cnt[e];
    if (n == 0) return;
    int wave = threadIdx.x >> 6, lane = threadIdx.x & 63;
    int h0 = (hb * 4 + wave) * 2;

    float wd0[32], wd1[32];
    {
        int r0 = e * HD + h0;
        int r1 = r0 + 1;
        int s0 = qscl[r0 * 64 + lane];
        int s1 = qscl[r1 * 64 + lane];
        const int* b0 = qblk + (long)r0 * 1024 + lane * 16;
        const int* b1 = qblk + (long)r1 * 1024 + lane * 16;
        #pragma unroll
        for (int i = 0; i < 16; ++i) {
            int b;
            b = b0[i]; wd0[2*i] = fp4_scaled(b & 15, s0); wd0[2*i+1] = fp4_scaled((b >> 4) & 15, s0);
            b = b1[i]; wd1[2*i] = fp4_scaled(b & 15, s1); wd1[2*i+1] = fp4_scaled((b >> 4) & 15, s1);
        }
    }
    float bv0 = bias[e * HD + h0], bv1 = bias[e * HD + h0 + 1];
    int base = pref[e];
    const int* pl = plist + e * 128;
    const float* wl = wlist + e * 128;
    for (int j = 0; j < n; ++j) {
        const float4* hr = (const float4*)(hbuf + (long)(base + j) * FD + lane * 32);
        float a0 = 0.f, a1 = 0.f;
        #pragma unroll
        for (int q = 0; q < 8; ++q) {
            float4 hv = hr[q];
            a0 = fmaf(wd0[4*q+0], hv.x, fmaf(wd0[4*q+1], hv.y, fmaf(wd0[4*q+2], hv.z, fmaf(wd0[4*q+3], hv.w, a0))));
            a1 = fmaf(wd1[4*q+0], hv.x, fmaf(wd1[4*q+1], hv.y, fmaf(wd1[4*q+2], hv.z, fmaf(wd1[4*q+3], hv.w, a1))));
        }
        #pragma unroll
        for (int off = 32; off > 0; off >>= 1) {
            a0 += __shfl_xor(a0, off);
            a1 += __shfl_xor(a1, off);
        }
        if (lane == 0) {
            int t = pl[j] >> 1;
            float wp = wl[j];
            atomicAdd(&out[t * HD + h0],     wp * (a0 + bv0));
            atomicAdd(&out[t * HD + h0 + 1], wp * (a1 + bv1));
        }
    }
}

extern "C" void kernel_launch(void* const* d_in, const int* in_sizes, int n_in,
                              void* d_out, int out_size, void* d_ws, size_t ws_size,
                              hipStream_t stream) {
    const float* x          = (const float*)d_in[0];
    const float* rw         = (const float*)d_in[1];
    const float* bias_gu    = (const float*)d_in[2];
    const float* bias_down  = (const float*)d_in[3];
    const int*   blocks_gu  = (const int*)d_in[4];
    const int*   scales_gu  = (const int*)d_in[5];
    const int*   blocks_down= (const int*)d_in[6];
    const int*   scales_down= (const int*)d_in[7];
    float* out = (float*)d_out;
    int*   wsI = (int*)d_ws;
    float* wsF = (float*)d_ws;

    (void)hipMemsetAsync(d_out, 0, sizeof(float) * 128 * HD, stream);
    routing_kernel<<<128, 256, 0, stream>>>(x, rw, wsI + TOPI_OFF, wsF + TOPW_OFF);
    build_kernel<<<1, 64, 0, stream>>>(wsI + TOPI_OFF, wsF + TOPW_OFF,
                                       wsI + CNT_OFF, wsI + PREF_OFF,
                                       wsI + PLIST_OFF, wsF + WLIST_OFF);
    gemm1_kernel<<<NE * 256, 256, 0, stream>>>(x, blocks_gu, scales_gu, bias_gu,
                                               wsI + CNT_OFF, wsI + PREF_OFF,
                                               wsI + PLIST_OFF, wsF + HBUF_OFF);
    gemm2_kernel<<<NE * 128, 256, 0, stream>>>(wsF + HBUF_OFF, blocks_down, scales_down, bias_down,
                                               wsI + CNT_OFF, wsI + PREF_OFF,
                                               wsI + PLIST_OFF, wsF + WLIST_OFF, out);
}

// Round 3
// 281.525 us; speedup vs baseline: 1.0027x; 1.0027x over previous
//
#include <hip/hip_runtime.h>
#include <math.h>

#define NE 16
#define HD 1024
#define FD 2048
#define TWO_F 4096
#define CHUNK 8

// ws layout (4-byte elements)
#define TOPI_OFF 0          // 256 int
#define TOPW_OFF 256        // 256 float
#define CNT_OFF  512        // 16 int
#define PREF_OFF 528        // 16 int
#define PLIST_OFF 544       // 16*128 int
#define SLOT_OFF 2592       // 256 int
#define HBUF_OFF 8192       // 256*2048 float
#define YBUF_OFF (HBUF_OFF + 256*2048)  // 256*1024 float

// decode one fp4 e2m1 nibble and fold in the e8m0 scale (2^(s-127)) via exponent math
__device__ __forceinline__ float fp4_scaled(int nib, int sbits) {
    int c = nib & 7;
    int e = c >> 1;
    int m = c & 1;
    int bits = ((e + sbits - 1) << 23) | ((e > 0) ? (m << 22) : 0);
    bits = (c == 0) ? 0 : bits;
    bits |= (nib & 8) << 28;   // sign
    return __int_as_float(bits);
}

__global__ void routing_kernel(const float* __restrict__ x, const float* __restrict__ rw,
                               int* __restrict__ top_idx, float* __restrict__ top_w) {
    int t = blockIdx.x;
    int tid = threadIdx.x;          // 256
    int e = tid >> 4, seg = tid & 15;
    const float* xr = x + t * HD + seg * 64;
    const float* wr = rw + e * HD + seg * 64;
    float p = 0.f;
    #pragma unroll 8
    for (int i = 0; i < 64; ++i) p += xr[i] * wr[i];
    __shared__ float part[16][16];
    __shared__ float logit[16];
    part[e][seg] = p;
    __syncthreads();
    if (tid < 16) {
        float s = 0.f;
        #pragma unroll
        for (int i = 0; i < 16; ++i) s += part[tid][i];
        logit[tid] = s;
    }
    __syncthreads();
    if (tid == 0) {
        int i0 = 0; float v0 = logit[0];
        #pragma unroll
        for (int i = 1; i < 16; ++i) { if (logit[i] > v0) { v0 = logit[i]; i0 = i; } }
        int i1 = -1; float v1 = -1e30f;
        #pragma unroll
        for (int i = 0; i < 16; ++i) { if (i != i0 && logit[i] > v1) { v1 = logit[i]; i1 = i; } }
        float w0 = 1.f / (1.f + expf(v1 - v0));
        float w1 = 1.f / (1.f + expf(v0 - v1));
        top_idx[t * 2]     = i0;  top_w[t * 2]     = w0;
        top_idx[t * 2 + 1] = i1;  top_w[t * 2 + 1] = w1;
    }
}

__global__ void build_kernel(const int* __restrict__ top_idx,
                             int* __restrict__ cnt, int* __restrict__ pref,
                             int* __restrict__ plist, int* __restrict__ slot) {
    int e = threadIdx.x;            // block 64
    __shared__ int scnt[16];
    __shared__ int spref[16];
    if (e < 16) {
        int c = 0;
        for (int p = 0; p < 256; ++p) if (top_idx[p] == e) c++;
        scnt[e] = c;
        cnt[e] = c;
    }
    __syncthreads();
    if (e == 0) {
        int s = 0;
        for (int i = 0; i < 16; ++i) { spref[i] = s; pref[i] = s; s += scnt[i]; }
    }
    __syncthreads();
    if (e < 16) {
        int c = 0;
        int b = spref[e];
        for (int p = 0; p < 256; ++p) {
            if (top_idx[p] == e) {
                plist[e * 128 + c] = p;
                slot[p] = b + c;
                c++;
            }
        }
    }
}

#define FMA4(acc, Wv, qq, a) \
    acc = fmaf(Wv[qq*4+0], a.x, fmaf(Wv[qq*4+1], a.y, fmaf(Wv[qq*4+2], a.z, fmaf(Wv[qq*4+3], a.w, acc))));

// gu GEMM + SwiGLU. 64 blocks/expert; block owns 32 f; wave owns 8 f (4 batches of 2).
__global__ __launch_bounds__(256, 2) void gemm1_kernel(
    const float* __restrict__ x, const int* __restrict__ qblk,
    const int* __restrict__ qscl, const float* __restrict__ bias,
    const int* __restrict__ cnt, const int* __restrict__ pref,
    const int* __restrict__ plist, float* __restrict__ hbuf) {
    int e = blockIdx.x >> 6;
    int fb = blockIdx.x & 63;
    int n = cnt[e];
    if (n == 0) return;
    int tid = threadIdx.x;
    int wave = tid >> 6, lane = tid & 63;
    __shared__ float sact[CHUNK * HD];   // 32 KB
    int fbase = fb * 32 + wave * 8;
    int base = pref[e];
    const int* pl = plist + e * 128;

    for (int c0 = 0; c0 < n; c0 += CHUNK) {
        int cb = min(CHUNK, n - c0);
        __syncthreads();
        for (int r = 0; r < cb; ++r) {
            int t = pl[c0 + r] >> 1;
            const float4* src = (const float4*)(x + (long)t * HD);
            ((float4*)(sact + r * HD))[tid] = src[tid];    // 256 float4 = 1024 floats
        }
        __syncthreads();

        for (int b = 0; b < 4; ++b) {
            int f0 = fbase + b * 2;
            long rg0 = (long)e * TWO_F + f0;        // gate rows rg0, rg0+1; up rows +FD
            float wg0[16], wg1[16], wu0[16], wu1[16];
            #pragma unroll
            for (int q = 0; q < 4; ++q) {
                int sb = q * 8 + (lane >> 3);
                int sg0 = qscl[rg0 * 32 + sb];
                int sg1 = qscl[(rg0 + 1) * 32 + sb];
                int su0 = qscl[(rg0 + FD) * 32 + sb];
                int su1 = qscl[(rg0 + FD + 1) * 32 + sb];
                int io = q * 64 + lane;
                int2 pg0 = ((const int2*)(qblk + rg0 * 512))[io];
                int2 pg1 = ((const int2*)(qblk + (rg0 + 1) * 512))[io];
                int2 pu0 = ((const int2*)(qblk + (rg0 + FD) * 512))[io];
                int2 pu1 = ((const int2*)(qblk + (rg0 + FD + 1) * 512))[io];
                wg0[q*4+0] = fp4_scaled(pg0.x & 15, sg0); wg0[q*4+1] = fp4_scaled((pg0.x >> 4) & 15, sg0);
                wg0[q*4+2] = fp4_scaled(pg0.y & 15, sg0); wg0[q*4+3] = fp4_scaled((pg0.y >> 4) & 15, sg0);
                wg1[q*4+0] = fp4_scaled(pg1.x & 15, sg1); wg1[q*4+1] = fp4_scaled((pg1.x >> 4) & 15, sg1);
                wg1[q*4+2] = fp4_scaled(pg1.y & 15, sg1); wg1[q*4+3] = fp4_scaled((pg1.y >> 4) & 15, sg1);
                wu0[q*4+0] = fp4_scaled(pu0.x & 15, su0); wu0[q*4+1] = fp4_scaled((pu0.x >> 4) & 15, su0);
                wu0[q*4+2] = fp4_scaled(pu0.y & 15, su0); wu0[q*4+3] = fp4_scaled((pu0.y >> 4) & 15, su0);
                wu1[q*4+0] = fp4_scaled(pu1.x & 15, su1); wu1[q*4+1] = fp4_scaled((pu1.x >> 4) & 15, su1);
                wu1[q*4+2] = fp4_scaled(pu1.y & 15, su1); wu1[q*4+3] = fp4_scaled((pu1.y >> 4) & 15, su1);
            }
            float bgv0 = bias[rg0], bgv1 = bias[rg0 + 1];
            float buv0 = bias[rg0 + FD], buv1 = bias[rg0 + FD + 1];

            for (int j = 0; j < cb; ++j) {
                const float4* av = (const float4*)(sact + j * HD);
                float ag0 = 0.f, ag1 = 0.f, au0 = 0.f, au1 = 0.f;
                #pragma unroll
                for (int q = 0; q < 4; ++q) {
                    float4 a = av[q * 64 + lane];
                    FMA4(ag0, wg0, q, a); FMA4(ag1, wg1, q, a);
                    FMA4(au0, wu0, q, a); FMA4(au1, wu1, q, a);
                }
                #pragma unroll
                for (int off = 32; off > 0; off >>= 1) {
                    ag0 += __shfl_xor(ag0, off);
                    ag1 += __shfl_xor(ag1, off);
                    au0 += __shfl_xor(au0, off);
                    au1 += __shfl_xor(au1, off);
                }
                if (lane == 0) {
                    float g0 = ag0 + bgv0, g1 = ag1 + bgv1;
                    float u0 = au0 + buv0, u1 = au1 + buv1;
                    float h0 = (g0 / (1.f + expf(-g0))) * u0;
                    float h1 = (g1 / (1.f + expf(-g1))) * u1;
                    float* hp = hbuf + (long)(base + c0 + j) * FD + f0;
                    hp[0] = h0; hp[1] = h1;
                }
            }
        }
    }
}

// down GEMM. 32 blocks/expert; block owns 32 h; wave owns 8 h (4 batches of 2).
__global__ __launch_bounds__(256, 2) void gemm2_kernel(
    const int* __restrict__ qblk, const int* __restrict__ qscl,
    const float* __restrict__ bias, const int* __restrict__ cnt,
    const int* __restrict__ pref, const float* __restrict__ hbuf,
    float* __restrict__ ybuf) {
    int e = blockIdx.x >> 5;
    int hb = blockIdx.x & 31;
    int n = cnt[e];
    if (n == 0) return;
    int tid = threadIdx.x;
    int wave = tid >> 6, lane = tid & 63;
    __shared__ float sact[CHUNK * FD];   // 64 KB
    int hbase = hb * 32 + wave * 8;
    int base = pref[e];

    for (int c0 = 0; c0 < n; c0 += CHUNK) {
        int cb = min(CHUNK, n - c0);
        __syncthreads();
        for (int r = 0; r < cb; ++r) {
            const float4* src = (const float4*)(hbuf + (long)(base + c0 + r) * FD);
            float4* dst = (float4*)(sact + r * FD);
            dst[tid] = src[tid];
            dst[tid + 256] = src[tid + 256];
        }
        __syncthreads();

        for (int b = 0; b < 4; ++b) {
            int h0 = hbase + b * 2;
            long r0 = (long)e * HD + h0;
            float wa[32], wb[32];
            #pragma unroll
            for (int q = 0; q < 8; ++q) {
                int sb = q * 8 + (lane >> 3);
                int s0 = qscl[r0 * 64 + sb];
                int s1 = qscl[(r0 + 1) * 64 + sb];
                int io = q * 64 + lane;
                int2 p0 = ((const int2*)(qblk + r0 * 1024))[io];
                int2 p1 = ((const int2*)(qblk + (r0 + 1) * 1024))[io];
                wa[q*4+0] = fp4_scaled(p0.x & 15, s0); wa[q*4+1] = fp4_scaled((p0.x >> 4) & 15, s0);
                wa[q*4+2] = fp4_scaled(p0.y & 15, s0); wa[q*4+3] = fp4_scaled((p0.y >> 4) & 15, s0);
                wb[q*4+0] = fp4_scaled(p1.x & 15, s1); wb[q*4+1] = fp4_scaled((p1.x >> 4) & 15, s1);
                wb[q*4+2] = fp4_scaled(p1.y & 15, s1); wb[q*4+3] = fp4_scaled((p1.y >> 4) & 15, s1);
            }
            float bv0 = bias[r0], bv1 = bias[r0 + 1];

            for (int j = 0; j < cb; ++j) {
                const float4* av = (const float4*)(sact + j * FD);
                float a0 = 0.f, a1 = 0.f;
                #pragma unroll
                for (int q = 0; q < 8; ++q) {
                    float4 a = av[q * 64 + lane];
                    FMA4(a0, wa, q, a); FMA4(a1, wb, q, a);
                }
                #pragma unroll
                for (int off = 32; off > 0; off >>= 1) {
                    a0 += __shfl_xor(a0, off);
                    a1 += __shfl_xor(a1, off);
                }
                if (lane == 0) {
                    float* yp = ybuf + (long)(base + c0 + j) * HD + h0;
                    yp[0] = a0 + bv0;
                    yp[1] = a1 + bv1;
                }
            }
        }
    }
}

__global__ void combine_kernel(const float* __restrict__ ybuf, const int* __restrict__ slot,
                               const float* __restrict__ topw, float* __restrict__ out) {
    int t = blockIdx.x;
    int i = threadIdx.x;   // 256, float4 each
    int s0 = slot[2 * t], s1 = slot[2 * t + 1];
    float w0 = topw[2 * t], w1 = topw[2 * t + 1];
    float4 a = ((const float4*)(ybuf + (long)s0 * HD))[i];
    float4 b = ((const float4*)(ybuf + (long)s1 * HD))[i];
    float4 o;
    o.x = w0 * a.x + w1 * b.x;
    o.y = w0 * a.y + w1 * b.y;
    o.z = w0 * a.z + w1 * b.z;
    o.w = w0 * a.w + w1 * b.w;
    ((float4*)(out + (long)t * HD))[i] = o;
}

extern "C" void kernel_launch(void* const* d_in, const int* in_sizes, int n_in,
                              void* d_out, int out_size, void* d_ws, size_t ws_size,
                              hipStream_t stream) {
    const float* x          = (const float*)d_in[0];
    const float* rw         = (const float*)d_in[1];
    const float* bias_gu    = (const float*)d_in[2];
    const float* bias_down  = (const float*)d_in[3];
    const int*   blocks_gu  = (const int*)d_in[4];
    const int*   scales_gu  = (const int*)d_in[5];
    const int*   blocks_down= (const int*)d_in[6];
    const int*   scales_down= (const int*)d_in[7];
    float* out = (float*)d_out;
    int*   wsI = (int*)d_ws;
    float* wsF = (float*)d_ws;

    routing_kernel<<<128, 256, 0, stream>>>(x, rw, wsI + TOPI_OFF, wsF + TOPW_OFF);
    build_kernel<<<1, 64, 0, stream>>>(wsI + TOPI_OFF, wsI + CNT_OFF, wsI + PREF_OFF,
                                       wsI + PLIST_OFF, wsI + SLOT_OFF);
    gemm1_kernel<<<NE * 64, 256, 0, stream>>>(x, blocks_gu, scales_gu, bias_gu,
                                              wsI + CNT_OFF, wsI + PREF_OFF,
                                              wsI + PLIST_OFF, wsF + HBUF_OFF);
    gemm2_kernel<<<NE * 32, 256, 0, stream>>>(blocks_down, scales_down, bias_down,
                                              wsI + CNT_OFF, wsI + PREF_OFF,
                                              wsF + HBUF_OFF, wsF + YBUF_OFF);
    combine_kernel<<<128, 256, 0, stream>>>(wsF + YBUF_OFF, wsI + SLOT_OFF,
                                            wsF + TOPW_OFF, out);
}

// Round 4
// 195.086 us; speedup vs baseline: 1.4470x; 1.4431x over previous
//
#include <hip/hip_runtime.h>
#include <math.h>

#define NE 16
#define HD 1024
#define FD 2048
#define TWO_F 4096

// ws layout (4-byte elements)
#define TOPI_OFF 0          // 256 int
#define TOPW_OFF 256        // 256 float
#define CNT_OFF  512        // 16 int
#define PREF_OFF 528        // 16 int
#define PLIST_OFF 544       // 16*128 int
#define SLOT_OFF 2592       // 256 int
#define HBUF_OFF 8192       // 256*2048 float
#define YBUF_OFF (HBUF_OFF + 256*2048)  // 256*1024 float

// decode one fp4 e2m1 nibble and fold in the e8m0 scale (2^(s-127)) via exponent math
__device__ __forceinline__ float fp4_scaled(int nib, int sbits) {
    int c = nib & 7;
    int e = c >> 1;
    int m = c & 1;
    int bits = ((e + sbits - 1) << 23) | ((e > 0) ? (m << 22) : 0);
    bits = (c == 0) ? 0 : bits;
    bits |= (nib & 8) << 28;   // sign
    return __int_as_float(bits);
}

__global__ void routing_kernel(const float* __restrict__ x, const float* __restrict__ rw,
                               int* __restrict__ top_idx, float* __restrict__ top_w) {
    int t = blockIdx.x;
    int tid = threadIdx.x;          // 256
    int e = tid >> 4, seg = tid & 15;
    const float* xr = x + t * HD + seg * 64;
    const float* wr = rw + e * HD + seg * 64;
    float p = 0.f;
    #pragma unroll 8
    for (int i = 0; i < 64; ++i) p += xr[i] * wr[i];
    __shared__ float part[16][16];
    __shared__ float logit[16];
    part[e][seg] = p;
    __syncthreads();
    if (tid < 16) {
        float s = 0.f;
        #pragma unroll
        for (int i = 0; i < 16; ++i) s += part[tid][i];
        logit[tid] = s;
    }
    __syncthreads();
    if (tid == 0) {
        int i0 = 0; float v0 = logit[0];
        #pragma unroll
        for (int i = 1; i < 16; ++i) { if (logit[i] > v0) { v0 = logit[i]; i0 = i; } }
        int i1 = -1; float v1 = -1e30f;
        #pragma unroll
        for (int i = 0; i < 16; ++i) { if (i != i0 && logit[i] > v1) { v1 = logit[i]; i1 = i; } }
        float w0 = 1.f / (1.f + expf(v1 - v0));
        float w1 = 1.f / (1.f + expf(v0 - v1));
        top_idx[t * 2]     = i0;  top_w[t * 2]     = w0;
        top_idx[t * 2 + 1] = i1;  top_w[t * 2 + 1] = w1;
    }
}

__global__ void build_kernel(const int* __restrict__ top_idx,
                             int* __restrict__ cnt, int* __restrict__ pref,
                             int* __restrict__ plist, int* __restrict__ slot) {
    int e = threadIdx.x;            // block 64
    __shared__ int scnt[16];
    __shared__ int spref[16];
    if (e < 16) {
        int c = 0;
        for (int p = 0; p < 256; ++p) if (top_idx[p] == e) c++;
        scnt[e] = c;
        cnt[e] = c;
    }
    __syncthreads();
    if (e == 0) {
        int s = 0;
        for (int i = 0; i < 16; ++i) { spref[i] = s; pref[i] = s; s += scnt[i]; }
    }
    __syncthreads();
    if (e < 16) {
        int c = 0;
        int b = spref[e];
        for (int p = 0; p < 256; ++p) {
            if (top_idx[p] == e) {
                plist[e * 128 + c] = p;
                slot[p] = b + c;
                c++;
            }
        }
    }
}

#define FMA4(acc, Wv, qq, a) \
    acc = fmaf(Wv[qq*4+0], a.x, fmaf(Wv[qq*4+1], a.y, fmaf(Wv[qq*4+2], a.z, fmaf(Wv[qq*4+3], a.w, acc))));

// gu GEMM + SwiGLU. Wave owns one f (gate row + up row); decode once, loop all tokens.
// lane's elements: h = q*256 + lane*4 + i  (q=0..3, i=0..3) -> coalesced int2 weights + float4 x.
__global__ __launch_bounds__(256, 4) void gemm1_kernel(
    const float* __restrict__ x, const int* __restrict__ qblk,
    const int* __restrict__ qscl, const float* __restrict__ bias,
    const int* __restrict__ cnt, const int* __restrict__ pref,
    const int* __restrict__ plist, float* __restrict__ hbuf) {
    int e = blockIdx.x >> 9;        // 512 blocks/expert
    int fb = blockIdx.x & 511;
    int n = cnt[e];
    if (n == 0) return;
    int wave = threadIdx.x >> 6, lane = threadIdx.x & 63;
    int f = fb * 4 + wave;
    long rg = (long)e * TWO_F + f;  // gate row
    long ru = rg + FD;              // up row

    float wg[16], wu[16];
    #pragma unroll
    for (int q = 0; q < 4; ++q) {
        int sg = qscl[rg * 32 + q * 8 + (lane >> 3)];
        int su = qscl[ru * 32 + q * 8 + (lane >> 3)];
        int2 pg = ((const int2*)(qblk + rg * 512))[q * 64 + lane];
        int2 pu = ((const int2*)(qblk + ru * 512))[q * 64 + lane];
        wg[q*4+0] = fp4_scaled(pg.x & 15, sg); wg[q*4+1] = fp4_scaled((pg.x >> 4) & 15, sg);
        wg[q*4+2] = fp4_scaled(pg.y & 15, sg); wg[q*4+3] = fp4_scaled((pg.y >> 4) & 15, sg);
        wu[q*4+0] = fp4_scaled(pu.x & 15, su); wu[q*4+1] = fp4_scaled((pu.x >> 4) & 15, su);
        wu[q*4+2] = fp4_scaled(pu.y & 15, su); wu[q*4+3] = fp4_scaled((pu.y >> 4) & 15, su);
    }
    float bg = bias[rg], bu = bias[ru];
    int base = pref[e];
    const int* pl = plist + e * 128;

    for (int j = 0; j < n; ++j) {
        int t = pl[j] >> 1;
        const float4* xr = (const float4*)(x + (long)t * HD);
        float ag = 0.f, au = 0.f;
        #pragma unroll
        for (int q = 0; q < 4; ++q) {
            float4 a = xr[q * 64 + lane];
            FMA4(ag, wg, q, a);
            FMA4(au, wu, q, a);
        }
        #pragma unroll
        for (int off = 32; off > 0; off >>= 1) {
            ag += __shfl_xor(ag, off);
            au += __shfl_xor(au, off);
        }
        if (lane == 0) {
            float g = ag + bg, u = au + bu;
            hbuf[(long)(base + j) * FD + f] = (g / (1.f + expf(-g))) * u;
        }
    }
}

// down GEMM. Wave owns one h row; decode once, loop all tokens.
// lane's elements: fidx = q*256 + lane*4 + i (q=0..7).
__global__ __launch_bounds__(256, 4) void gemm2_kernel(
    const int* __restrict__ qblk, const int* __restrict__ qscl,
    const float* __restrict__ bias, const int* __restrict__ cnt,
    const int* __restrict__ pref, const float* __restrict__ hbuf,
    float* __restrict__ ybuf) {
    int e = blockIdx.x >> 8;        // 256 blocks/expert
    int hb = blockIdx.x & 255;
    int n = cnt[e];
    if (n == 0) return;
    int wave = threadIdx.x >> 6, lane = threadIdx.x & 63;
    int h = hb * 4 + wave;
    long r = (long)e * HD + h;

    float wd[32];
    #pragma unroll
    for (int q = 0; q < 8; ++q) {
        int s = qscl[r * 64 + q * 8 + (lane >> 3)];
        int2 p = ((const int2*)(qblk + r * 1024))[q * 64 + lane];
        wd[q*4+0] = fp4_scaled(p.x & 15, s); wd[q*4+1] = fp4_scaled((p.x >> 4) & 15, s);
        wd[q*4+2] = fp4_scaled(p.y & 15, s); wd[q*4+3] = fp4_scaled((p.y >> 4) & 15, s);
    }
    float bv = bias[r];
    int base = pref[e];

    for (int j = 0; j < n; ++j) {
        const float4* hr = (const float4*)(hbuf + (long)(base + j) * FD);
        float a = 0.f;
        #pragma unroll
        for (int q = 0; q < 8; ++q) {
            float4 v = hr[q * 64 + lane];
            FMA4(a, wd, q, v);
        }
        #pragma unroll
        for (int off = 32; off > 0; off >>= 1) {
            a += __shfl_xor(a, off);
        }
        if (lane == 0) {
            ybuf[(long)(base + j) * HD + h] = a + bv;
        }
    }
}

__global__ void combine_kernel(const float* __restrict__ ybuf, const int* __restrict__ slot,
                               const float* __restrict__ topw, float* __restrict__ out) {
    int t = blockIdx.x;
    int i = threadIdx.x;   // 256, float4 each
    int s0 = slot[2 * t], s1 = slot[2 * t + 1];
    float w0 = topw[2 * t], w1 = topw[2 * t + 1];
    float4 a = ((const float4*)(ybuf + (long)s0 * HD))[i];
    float4 b = ((const float4*)(ybuf + (long)s1 * HD))[i];
    float4 o;
    o.x = w0 * a.x + w1 * b.x;
    o.y = w0 * a.y + w1 * b.y;
    o.z = w0 * a.z + w1 * b.z;
    o.w = w0 * a.w + w1 * b.w;
    ((float4*)(out + (long)t * HD))[i] = o;
}

extern "C" void kernel_launch(void* const* d_in, const int* in_sizes, int n_in,
                              void* d_out, int out_size, void* d_ws, size_t ws_size,
                              hipStream_t stream) {
    const float* x          = (const float*)d_in[0];
    const float* rw         = (const float*)d_in[1];
    const float* bias_gu    = (const float*)d_in[2];
    const float* bias_down  = (const float*)d_in[3];
    const int*   blocks_gu  = (const int*)d_in[4];
    const int*   scales_gu  = (const int*)d_in[5];
    const int*   blocks_down= (const int*)d_in[6];
    const int*   scales_down= (const int*)d_in[7];
    float* out = (float*)d_out;
    int*   wsI = (int*)d_ws;
    float* wsF = (float*)d_ws;

    routing_kernel<<<128, 256, 0, stream>>>(x, rw, wsI + TOPI_OFF, wsF + TOPW_OFF);
    build_kernel<<<1, 64, 0, stream>>>(wsI + TOPI_OFF, wsI + CNT_OFF, wsI + PREF_OFF,
                                       wsI + PLIST_OFF, wsI + SLOT_OFF);
    gemm1_kernel<<<NE * 512, 256, 0, stream>>>(x, blocks_gu, scales_gu, bias_gu,
                                               wsI + CNT_OFF, wsI + PREF_OFF,
                                               wsI + PLIST_OFF, wsF + HBUF_OFF);
    gemm2_kernel<<<NE * 256, 256, 0, stream>>>(blocks_down, scales_down, bias_down,
                                               wsI + CNT_OFF, wsI + PREF_OFF,
                                               wsF + HBUF_OFF, wsF + YBUF_OFF);
    combine_kernel<<<128, 256, 0, stream>>>(wsF + YBUF_OFF, wsI + SLOT_OFF,
                                            wsF + TOPW_OFF, out);
}